// Round 13
// baseline (186.472 us; speedup 1.0000x reference)
//
#include <hip/hip_runtime.h>

#define N 8192
#define DIN 64
#define DOUT 128
#define KNN 16
#define MSAMP 2048         /* presample columns, stride 4 */
#define NBX 8              /* j-split in main scan */
#define CAND_R 96          /* slots per (row, bx) region (atomic append) */
#define CAND_C (NBX * CAND_R)   /* 768 per row */
#define EPS 1.0f           /* candidate-gate margin (passed r8-r12) */
#define DELTA_Q 64         /* verify-gate margin: 0.5 in dist units */
#define VCAP 128           /* verify-list capacity (expect ~45) */
#define ROWS_PRE 16

typedef unsigned long long u64;
typedef __attribute__((ext_vector_type(8))) short bf16x8;
typedef __attribute__((ext_vector_type(4))) float floatx4;

__device__ __forceinline__ unsigned mono(float f) {
    unsigned u = __float_as_uint(f);
    return (u & 0x80000000u) ? ~u : (u | 0x80000000u);
}
__device__ __forceinline__ unsigned short f2bf(float f) {   // RNE float->bf16
    unsigned u = __float_as_uint(f);
    return (unsigned short)((u + 0x7FFFu + ((u >> 16) & 1u)) >> 16);
}
__device__ __forceinline__ unsigned qdist(float dist) {     // round-up quant
    int q = (int)(dist * 128.0f) + 2;
    q = max(q, 0); return (unsigned)min(q, 65535);
}

// K1: fused pre: sq, sqs, bf16 Xh, U = x@(W1a-W1b)+b1, V = x@W1b.
__global__ __launch_bounds__(256) void k_pre(const float* __restrict__ x,
                                             const float* __restrict__ W1,
                                             const float* __restrict__ b1,
                                             float* __restrict__ sq,
                                             float* __restrict__ sqs,
                                             unsigned short* __restrict__ Xh,
                                             float* __restrict__ U,
                                             float* __restrict__ V) {
    __shared__ float xs[ROWS_PRE][DIN];
    int t = threadIdx.x;
    int r0 = blockIdx.x * ROWS_PRE;
    float4 xv = ((const float4*)x)[(size_t)r0 * (DIN / 4) + t];
    ((float4*)xs)[t] = xv;
    ushort4 h4;
    h4.x = f2bf(xv.x); h4.y = f2bf(xv.y);
    h4.z = f2bf(xv.z); h4.w = f2bf(xv.w);
    *(ushort4*)&Xh[r0 * DIN + t * 4] = h4;
    __syncthreads();
    if (t < ROWS_PRE) {
        const float4* xr = (const float4*)xs[t];
        float s0 = 0.f, s1 = 0.f, s2 = 0.f, s3 = 0.f;
#pragma unroll
        for (int q = 0; q < DIN / 4; ++q) {
            float4 a = xr[q];
            s0 = fmaf(a.x, a.x, s0); s1 = fmaf(a.y, a.y, s1);
            s2 = fmaf(a.z, a.z, s2); s3 = fmaf(a.w, a.w, s3);
        }
        float sv = (s0 + s1) + (s2 + s3);
        sq[r0 + t] = sv;
        if ((t & 3) == 0) sqs[(r0 + t) >> 2] = sv;   // sampled rows j = 4*scol
    }
    int o = t & 127, g = t >> 7;
    float aU[8], aV[8];
#pragma unroll
    for (int u = 0; u < 8; ++u) { aU[u] = 0.f; aV[u] = 0.f; }
    for (int kk = 0; kk < DIN; ++kk) {
        float whi = W1[kk * DOUT + o];
        float wlo = W1[(DIN + kk) * DOUT + o];
        float wd = whi - wlo;
#pragma unroll
        for (int u = 0; u < 8; ++u) {
            float xvv = xs[g * 8 + u][kk];
            aU[u] = fmaf(xvv, wd, aU[u]);
            aV[u] = fmaf(xvv, wlo, aV[u]);
        }
    }
    float bb = b1[o];
#pragma unroll
    for (int u = 0; u < 8; ++u) {
        int r = r0 + g * 8 + u;
        U[(size_t)r * DOUT + o] = aU[u] + bb;
        V[(size_t)r * DOUT + o] = aV[u];
    }
}

// K2a: MFMA presample (HH only), swapped operands -> packed u64 stores.
__global__ __launch_bounds__(256, 4) void k_presample(const unsigned short* __restrict__ Xh,
                                                      const float* __restrict__ sq,
                                                      const float* __restrict__ sqs,
                                                      unsigned short* __restrict__ prekq) {
    __shared__ __align__(16) short ldsH[64 * 72];
    int tid = threadIdx.x, w = tid >> 6, l = tid & 63;
    int m = l & 15, ko = (l >> 4) * 8, quad = l >> 4;
    int bx = blockIdx.x;
    int rt = blockIdx.y * 4 + w;
    int irow = rt * 16 + m;
    size_t arow = (size_t)irow * DIN;
    bf16x8 iH0 = *(const bf16x8*)(Xh + arow + ko);        // i-row frag (B)
    bf16x8 iH1 = *(const bf16x8*)(Xh + arow + 32 + ko);
    float si = sq[irow];
    int srw = tid >> 3, scol8 = (tid & 7) * 8;
    for (int st = 0; st < 4; ++st) {
        int sbase = bx * 256 + st * 64;
        __syncthreads();
        *(bf16x8*)&ldsH[srw * 72 + scol8] =
            *(const bf16x8*)(Xh + (size_t)(4 * (sbase + srw)) * DIN + scol8);
        *(bf16x8*)&ldsH[(srw + 32) * 72 + scol8] =
            *(const bf16x8*)(Xh + (size_t)(4 * (sbase + srw + 32)) * DIN + scol8);
        __syncthreads();
#pragma unroll
        for (int it = 0; it < 4; ++it) {
            int br = it * 16 + m;
            bf16x8 sH0 = *(const bf16x8*)&ldsH[br * 72 + ko];   // sampled (A)
            bf16x8 sH1 = *(const bf16x8*)&ldsH[br * 72 + 32 + ko];
            floatx4 acc = {0.f, 0.f, 0.f, 0.f};
            acc = __builtin_amdgcn_mfma_f32_16x16x32_bf16(sH0, iH0, acc, 0, 0, 0);
            acc = __builtin_amdgcn_mfma_f32_16x16x32_bf16(sH1, iH1, acc, 0, 0, 0);
            int sc0 = sbase + it * 16 + quad * 4;       // 4 consecutive scols
            float4 sj = *(const float4*)(sqs + sc0);
            unsigned q0 = qdist(fmaf(-2.0f, acc[0], si + sj.x));
            unsigned q1 = qdist(fmaf(-2.0f, acc[1], si + sj.y));
            unsigned q2 = qdist(fmaf(-2.0f, acc[2], si + sj.z));
            unsigned q3 = qdist(fmaf(-2.0f, acc[3], si + sj.w));
            u64 pk = (u64)q0 | ((u64)q1 << 16) | ((u64)q2 << 32) | ((u64)q3 << 48);
            *(u64*)(prekq + (size_t)irow * MSAMP + sc0) = pk;
        }
    }
}

// K2b: tau[row] = exact 16th-smallest sampled quantized dist / 128, via
// 16-step radix-select (ballot+popc, no shuffle chains).
__global__ __launch_bounds__(256, 4) void k_tau(const unsigned short* __restrict__ prekq,
                                                float* __restrict__ tauf) {
    int w = threadIdx.x >> 6, l = threadIdx.x & 63;
    int row = blockIdx.x * 4 + w;
    unsigned v[MSAMP / 64];
#pragma unroll
    for (int u = 0; u < MSAMP / 64; ++u)
        v[u] = prekq[(size_t)row * MSAMP + l + 64 * u];
    unsigned p = 0;                               // invariant: #{q < p} < 16
#pragma unroll
    for (int b = 15; b >= 0; --b) {
        unsigned c16 = p | (1u << b);
        int cnt = 0;
#pragma unroll
        for (int u = 0; u < MSAMP / 64; ++u)
            cnt += __popcll(__ballot(v[u] < c16));
        if (cnt < 16) p = c16;                    // wave-uniform
    }
    if (l == 0) tauf[row] = (float)p * (1.0f / 128.0f);
}

// K2c: MFMA main scan with LDS-atomic slot append (no ballot machinery).
// Final output is a pure function of the candidate SET (rank-select on exact
// keys downstream), so atomic slot order is harmless; CAND_R=96 makes
// overflow probability negligible.
__global__ __launch_bounds__(256, 4) void k_main(const unsigned short* __restrict__ Xh,
                                                 const float* __restrict__ sq,
                                                 const float* __restrict__ tauf,
                                                 unsigned* __restrict__ cand,
                                                 unsigned* __restrict__ cntpart) {
    __shared__ __align__(16) short ldsH[64 * 72];
    __shared__ int cnt[64];
    int tid = threadIdx.x, w = tid >> 6, l = tid & 63;
    int m = l & 15, ko = (l >> 4) * 8, quad = l >> 4;
    int bx = blockIdx.x;
    int rt = blockIdx.y * 4 + w;
    if (tid < 64) cnt[tid] = 0;
    size_t arow = (size_t)(rt * 16 + m) * DIN;
    bf16x8 aH0 = *(const bf16x8*)(Xh + arow + ko);
    bf16x8 aH1 = *(const bf16x8*)(Xh + arow + 32 + ko);
    int rg[4], lrow[4]; float T[4]; float si[4];
#pragma unroll
    for (int reg = 0; reg < 4; ++reg) {
        rg[reg] = rt * 16 + quad * 4 + reg;
        lrow[reg] = w * 16 + quad * 4 + reg;
        si[reg] = sq[rg[reg]];
        T[reg] = tauf[rg[reg]] + EPS - si[reg];
    }
    int srw = tid >> 3, scol8 = (tid & 7) * 8;

    for (int st = 0; st < 16; ++st) {
        int jbase = bx * 1024 + st * 64;
        __syncthreads();
        *(bf16x8*)&ldsH[srw * 72 + scol8] =
            *(const bf16x8*)(Xh + (size_t)(jbase + srw) * DIN + scol8);
        *(bf16x8*)&ldsH[(srw + 32) * 72 + scol8] =
            *(const bf16x8*)(Xh + (size_t)(jbase + srw + 32) * DIN + scol8);
        __syncthreads();
#pragma unroll
        for (int it = 0; it < 4; ++it) {
            int br = it * 16 + m;
            bf16x8 bH0 = *(const bf16x8*)&ldsH[br * 72 + ko];
            bf16x8 bH1 = *(const bf16x8*)&ldsH[br * 72 + 32 + ko];
            floatx4 acc = {0.f, 0.f, 0.f, 0.f};
            acc = __builtin_amdgcn_mfma_f32_16x16x32_bf16(aH0, bH0, acc, 0, 0, 0);
            acc = __builtin_amdgcn_mfma_f32_16x16x32_bf16(aH1, bH1, acc, 0, 0, 0);
            int jcol = jbase + it * 16 + m;
            float sqj = sq[jcol];
#pragma unroll
            for (int reg = 0; reg < 4; ++reg) {
                float tv = fmaf(-2.0f, acc[reg], sqj);   // dist - si
                if (tv <= T[reg]) {                      // rare (~1.8%/lane)
                    int slot = atomicAdd(&cnt[lrow[reg]], 1);
                    if (slot < CAND_R)
                        cand[(size_t)rg[reg] * CAND_C + bx * CAND_R + slot] =
                            (qdist(tv + si[reg]) << 16) | (unsigned)jcol;
                }
            }
        }
    }
    __syncthreads();
    if (tid < 64)
        cntpart[(blockIdx.y * 64 + tid) * NBX + bx] =
            (unsigned)min(cnt[tid], CAND_R);
}

// K3: fused verify-gated exact top-16 + aggregation + output GEMM.
// One wave per row (4 rows/block): radix-select q16 -> verify
// {q <= q16+DELTA_Q} -> exact striped fp32 dot (order == r1-r12) ->
// all-pairs rank-select into LDS knn -> barrier ->
// agg = mean relu(U_i + V_j), out = agg@W2 + b2 (k order 0..127 == r12).
__global__ __launch_bounds__(256) void k_exact_agg(const float* __restrict__ x,
                                                   const float* __restrict__ sq,
                                                   const unsigned* __restrict__ cntpart,
                                                   const unsigned* __restrict__ cand,
                                                   const float* __restrict__ U,
                                                   const float* __restrict__ V,
                                                   const float* __restrict__ W2,
                                                   const float* __restrict__ b2,
                                                   float* __restrict__ out) {
    __shared__ unsigned cj[4][CAND_C];          // 12 KB
    __shared__ unsigned short vlist[4][VCAP];   // 1 KB
    __shared__ u64 ekeys[4][VCAP];              // 4 KB
    __shared__ int knnl[4][KNN];                // 256 B
    __shared__ float ag[4][DOUT];               // 2 KB
    int t = threadIdx.x;
    int w = t >> 6, l = t & 63;
    int row = blockIdx.x * 4 + w;
    int base = 0;
#pragma unroll
    for (int b = 0; b < NBX; ++b) {             // compact candidate list
        int c = (int)cntpart[row * NBX + b];    // wave-uniform -> scalar
        c = min(c, CAND_R);
        for (int s = l; s < c; s += 64)
            cj[w][base + s] = cand[(size_t)row * CAND_C + b * CAND_R + s];
        base += c;
    }
    unsigned kk[CAND_C / 64], qq[CAND_C / 64];
#pragma unroll
    for (int u = 0; u < CAND_C / 64; ++u) {
        int idx = l + 64 * u;
        kk[u] = (idx < base) ? cj[w][idx] : 0xFFFFFFFFu;
        qq[u] = (idx < base) ? (kk[u] >> 16) : 0xFFFFFFFFu;
    }
    unsigned p = 0;                             // radix-select q16
#pragma unroll
    for (int b = 15; b >= 0; --b) {
        unsigned c16 = p | (1u << b);
        int cnt = 0;
#pragma unroll
        for (int u = 0; u < CAND_C / 64; ++u)
            cnt += __popcll(__ballot(qq[u] < c16));
        if (cnt < 16) p = c16;
    }
    unsigned thr = p + DELTA_Q;                 // verify gate on q
    int nv = 0;
    u64 lm = (l == 63) ? 0xFFFFFFFFFFFFFFFFull >> 1 : (1ull << l) - 1ull;
#pragma unroll
    for (int u = 0; u < CAND_C / 64; ++u) {
        bool pred = qq[u] <= thr;               // invalid qq -> false
        u64 bal = __ballot(pred);
        int slot = nv + __popcll(bal & lm);
        if (pred && slot < VCAP) vlist[w][slot] = (unsigned short)(kk[u] & 0xFFFFu);
        nv += __popcll(bal);
    }
    nv = min(nv, VCAP);
    float sqi = sq[row];
    const float* xi = x + (size_t)row * DIN;    // wave-uniform -> SGPRs
#pragma unroll
    for (int r = 0; r < VCAP / 64; ++r) {
        int v = l + 64 * r;
        if (v < nv) {
            int j = (int)vlist[w][v];
            const float4* bj = (const float4*)(x + (size_t)j * DIN);
            float4 rb[16];
#pragma unroll
            for (int q = 0; q < DIN / 4; ++q) rb[q] = bj[q];
            float s0 = 0.f, s1 = 0.f, s2 = 0.f, s3 = 0.f;
#pragma unroll
            for (int q = 0; q < DIN / 4; ++q) {  // striped order == r1-r12
                s0 = fmaf(xi[4 * q + 0], rb[q].x, s0);
                s1 = fmaf(xi[4 * q + 1], rb[q].y, s1);
                s2 = fmaf(xi[4 * q + 2], rb[q].z, s2);
                s3 = fmaf(xi[4 * q + 3], rb[q].w, s3);
            }
            float d = (s0 + s1) + (s2 + s3);
            float dist = fmaf(-2.0f, d, sqi + sq[j]);
            ekeys[w][v] = ((u64)mono(dist) << 32) | (unsigned)j;
        }
    }
#pragma unroll
    for (int r = 0; r < VCAP / 64; ++r) {       // all-pairs rank-select
        int v = l + 64 * r;
        if (v < nv) {
            u64 mykey = ekeys[w][v];
            int rank = 0;
            for (int i = 0; i < nv; ++i)
                rank += (ekeys[w][i] < mykey) ? 1 : 0;
            if (rank < KNN)
                knnl[w][rank] = (int)(unsigned)(mykey & 0xFFFFFFFFull);
        }
    }
    __syncthreads();
    // ---- aggregation + output GEMM (2 rows per thread) ----
    int o = t & 127, g = t >> 7;
    int i0 = blockIdx.x * 4;
#pragma unroll
    for (int rr = 0; rr < 2; ++rr) {
        int rl = g * 2 + rr;
        float u = U[(size_t)(i0 + rl) * DOUT + o];
        float acc = 0.f;
#pragma unroll
        for (int q = 0; q < KNN; ++q)
            acc += fmaxf(u + V[(size_t)knnl[rl][q] * DOUT + o], 0.0f);
        ag[rl][o] = acc * (1.0f / KNN);
    }
    __syncthreads();
    float a2[2] = {0.f, 0.f};
#pragma unroll 4
    for (int k = 0; k < DOUT; ++k) {            // k ascending == r12 order
        float wv = W2[k * DOUT + o];
        a2[0] = fmaf(ag[g * 2 + 0][k], wv, a2[0]);
        a2[1] = fmaf(ag[g * 2 + 1][k], wv, a2[1]);
    }
    float bb = b2[o];
    out[(size_t)(i0 + g * 2 + 0) * DOUT + o] = a2[0] + bb;
    out[(size_t)(i0 + g * 2 + 1) * DOUT + o] = a2[1] + bb;
}

extern "C" void kernel_launch(void* const* d_in, const int* in_sizes, int n_in,
                              void* d_out, int out_size, void* d_ws, size_t ws_size,
                              hipStream_t stream) {
    const float* x  = (const float*)d_in[0];
    const float* W1 = (const float*)d_in[1];
    const float* b1 = (const float*)d_in[2];
    const float* W2 = (const float*)d_in[3];
    const float* b2 = (const float*)d_in[4];
    float* out = (float*)d_out;

    char* ws = (char*)d_ws;
    float*          sq      = (float*)(ws);                      // 32 KB
    float*          sqs     = (float*)(ws + 32768);              // 8 KB
    float*          tauf    = (float*)(ws + 40960);              // 32 KB
    unsigned short* Xh      = (unsigned short*)(ws + 655360);    // 1 MB
    unsigned*       cntpart = (unsigned*)(ws + 1703936);         // 256 KB
    float*          U       = (float*)(ws + 2097152);            // 4 MB
    float*          V       = (float*)(ws + 6291456);            // 4 MB
    char*           region  = ws + 10485760;                     // 32 MB shared:
    unsigned short* prekq   = (unsigned short*)region;           //  dead after k_tau
    unsigned*       cand    = (unsigned*)region;                 //  k_main (25.2 MB)
    // total ws use ~35.7 MB (<= proven 42.8 envelope)

    k_pre<<<N / ROWS_PRE, 256, 0, stream>>>(x, W1, b1, sq, sqs, Xh, U, V);
    k_presample<<<dim3(8, 128), 256, 0, stream>>>(Xh, sq, sqs, prekq);
    k_tau<<<N / 4, 256, 0, stream>>>(prekq, tauf);
    k_main<<<dim3(NBX, 128), 256, 0, stream>>>(Xh, sq, tauf, cand, cntpart);
    k_exact_agg<<<N / 4, 256, 0, stream>>>(x, sq, cntpart, cand, U, V, W2, b2, out);
}